// Round 7
// baseline (47959.070 us; speedup 1.0000x reference)
//
#include <hip/hip_runtime.h>
#include <hip/hip_cooperative_groups.h>

namespace cg = cooperative_groups;

typedef _Float16 half_t;
typedef _Float16 half8 __attribute__((ext_vector_type(8)));
typedef float floatx4 __attribute__((ext_vector_type(4)));

#define NSTEP 512
#define INV2048 (1.0f / 2048.0f)
#define WS_NEED (67108864 + 4 * 262144)

// blob layout: [layer(2)][wg(128)][wave(4)][frag(32)][hilo(2)][lane(64)][i(8)]
// frag = kk*2 + mt; A[mloc][k]: mloc = mt*16 + (lane&15), k = kk*32 + (lane>>4)*8 + i.
// mloc -> gate = mloc>>3, unit u = mloc&7; global row = gate*1024 + wg*8 + u.
// Wave wv covers k in [wv*512, wv*512+512); k<1024 -> W_ih, else W_hh.
__global__ void conv_w(const float* __restrict__ Wih, const float* __restrict__ Whh,
                       half_t* __restrict__ wblob) {
  long e = (long)blockIdx.x * 256 + threadIdx.x;  // 16,777,216 logical elements
  int i  = (int)(e & 7);
  int l  = (int)((e >> 3) & 63);
  int f  = (int)((e >> 9) & 31);
  int w  = (int)((e >> 14) & 3);
  int wg = (int)((e >> 16) & 127);
  int layer = (int)(e >> 23);
  int mt = f & 1, kk = f >> 1;
  int mloc = mt * 16 + (l & 15);
  int grow = (mloc >> 3) * 1024 + wg * 8 + (mloc & 7);
  int kglob = w * 512 + kk * 32 + ((l >> 4) * 8) + i;
  long base = ((long)layer << 22) + (long)grow * 1024;
  float v = (kglob < 1024) ? Wih[base + kglob] : Whh[base + (kglob - 1024)];
  half_t hi = (half_t)v;
  half_t lo = (half_t)((v - (float)hi) * 2048.0f);  // residual, pre-scaled 2^11
  long o = ((e >> 9) << 10) + (e & 511);
  wblob[o] = hi;
  wblob[o + 512] = lo;
}

__device__ __forceinline__ float sigm(float x) { return 1.f / (1.f + __expf(-x)); }
__device__ __forceinline__ float tanh_f(float x) {
  x = fminf(15.f, fmaxf(-15.f, x));
  float e = __expf(-2.f * x);
  return (1.f - e) / (1.f + e);
}

// Persistent cooperative kernel. 256 WGs x 256 threads.
// WGs 0..127: layer 1 at step t = p.  WGs 128..255: layer 2 at step t = p-1.
__launch_bounds__(256, 1)
__global__ void lstm_main(const int* __restrict__ tokens, const float* __restrict__ emb,
                          const float* __restrict__ bih, const float* __restrict__ bhh,
                          const half_t* __restrict__ wblob,
                          half_t* __restrict__ h1hi, half_t* __restrict__ h1lo,
                          half_t* __restrict__ h2hi, half_t* __restrict__ h2lo,
                          float* __restrict__ out) {
  __shared__ float part[4][32][68];
  cg::grid_group grid = cg::this_grid();
  const int wgid = blockIdx.x;
  const int layer = wgid >> 7;
  const int wg = wgid & 127;
  const int tid = (int)threadIdx.x;
  const int wv = tid >> 6;
  const int lane = tid & 63;

  float c0 = 0.f, c1 = 0.f;  // cell state lives in registers all 512 steps
  const half_t* wstream = wblob + ((long)(layer * 128 + wg) * 4 + wv) * 32768;

  float bsum[4];
  {
    int u = tid & 7;
    for (int g = 0; g < 4; ++g) {
      int bi = layer * 4096 + g * 1024 + wg * 8 + u;
      bsum[g] = bih[bi] + bhh[bi];
    }
  }

  for (int p = 0; p <= NSTEP; ++p) {
    const bool active = (layer == 0) ? (p < NSTEP) : (p >= 1);
    const int t = (layer == 0) ? p : (p - 1);
    floatx4 zero = {0.f, 0.f, 0.f, 0.f};
    floatx4 acc_h[2][4], acc_l[2][4];
    for (int a = 0; a < 2; ++a)
      for (int b = 0; b < 4; ++b) { acc_h[a][b] = zero; acc_l[a][b] = zero; }

    if (active) {
      const bool skipH = (wv >= 2) && (t == 0);  // h_{t-1} = 0 at t==0
      if (!skipH) {
        if (layer == 0 && wv < 2) {
          // x-part from f32 embedding (token 0 -> zero row), split hi/lo on the fly
          int tk[4];
          #pragma unroll
          for (int nt = 0; nt < 4; ++nt) tk[nt] = tokens[t * 64 + nt * 16 + (lane & 15)];
          #pragma unroll 2
          for (int kk = 0; kk < 16; ++kk) {
            const half_t* fb0 = wstream + (kk * 2 + 0) * 1024;
            const half_t* fb1 = wstream + (kk * 2 + 1) * 1024;
            half8 a0h = *(const half8*)(fb0 + lane * 8);
            half8 a0l = *(const half8*)(fb0 + 512 + lane * 8);
            half8 a1h = *(const half8*)(fb1 + lane * 8);
            half8 a1l = *(const half8*)(fb1 + 512 + lane * 8);
            int kb = wv * 512 + kk * 32 + ((lane >> 4) * 8);
            #pragma unroll
            for (int nt = 0; nt < 4; ++nt) {
              int tok = tk[nt];
              const float* src = emb + (long)tok * 1024 + kb;
              floatx4 x0 = *(const floatx4*)(src);
              floatx4 x1 = *(const floatx4*)(src + 4);
              float msk = (tok == 0) ? 0.f : 1.f;
              half8 bh, bl;
              #pragma unroll
              for (int q = 0; q < 4; ++q) {
                float v0 = x0[q] * msk;
                float v1 = x1[q] * msk;
                half_t h0 = (half_t)v0, h1v = (half_t)v1;
                bh[q] = h0;     bh[q + 4] = h1v;
                bl[q] = (half_t)((v0 - (float)h0) * 2048.f);
                bl[q + 4] = (half_t)((v1 - (float)h1v) * 2048.f);
              }
              acc_h[0][nt] = __builtin_amdgcn_mfma_f32_16x16x32_f16(a0h, bh, acc_h[0][nt], 0, 0, 0);
              acc_h[1][nt] = __builtin_amdgcn_mfma_f32_16x16x32_f16(a1h, bh, acc_h[1][nt], 0, 0, 0);
              acc_l[0][nt] = __builtin_amdgcn_mfma_f32_16x16x32_f16(a0h, bl, acc_l[0][nt], 0, 0, 0);
              acc_l[0][nt] = __builtin_amdgcn_mfma_f32_16x16x32_f16(a0l, bh, acc_l[0][nt], 0, 0, 0);
              acc_l[1][nt] = __builtin_amdgcn_mfma_f32_16x16x32_f16(a1h, bl, acc_l[1][nt], 0, 0, 0);
              acc_l[1][nt] = __builtin_amdgcn_mfma_f32_16x16x32_f16(a1l, bh, acc_l[1][nt], 0, 0, 0);
            }
          }
        } else {
          // f16 hi/lo activation buffers
          const half_t *abh, *abl;
          int kofs;
          if (wv < 2) {  // layer==1 x-part = h1 at t (written phase p-1)
            abh = h1hi + ((p - 1) & 1) * 65536;
            abl = h1lo + ((p - 1) & 1) * 65536;
            kofs = wv * 512;
          } else {       // recurrent h-part (own layer, t-1)
            abh = (layer == 0 ? h1hi : h2hi) + ((p - 1) & 1) * 65536;
            abl = (layer == 0 ? h1lo : h2lo) + ((p - 1) & 1) * 65536;
            kofs = (wv - 2) * 512;
          }
          #pragma unroll 2
          for (int kk = 0; kk < 16; ++kk) {
            const half_t* fb0 = wstream + (kk * 2 + 0) * 1024;
            const half_t* fb1 = wstream + (kk * 2 + 1) * 1024;
            half8 a0h = *(const half8*)(fb0 + lane * 8);
            half8 a0l = *(const half8*)(fb0 + 512 + lane * 8);
            half8 a1h = *(const half8*)(fb1 + lane * 8);
            half8 a1l = *(const half8*)(fb1 + 512 + lane * 8);
            int kb = kofs + kk * 32 + ((lane >> 4) * 8);
            #pragma unroll
            for (int nt = 0; nt < 4; ++nt) {
              int n = nt * 16 + (lane & 15);
              half8 bh = *(const half8*)(abh + n * 1024 + kb);
              half8 bl = *(const half8*)(abl + n * 1024 + kb);
              acc_h[0][nt] = __builtin_amdgcn_mfma_f32_16x16x32_f16(a0h, bh, acc_h[0][nt], 0, 0, 0);
              acc_h[1][nt] = __builtin_amdgcn_mfma_f32_16x16x32_f16(a1h, bh, acc_h[1][nt], 0, 0, 0);
              acc_l[0][nt] = __builtin_amdgcn_mfma_f32_16x16x32_f16(a0h, bl, acc_l[0][nt], 0, 0, 0);
              acc_l[0][nt] = __builtin_amdgcn_mfma_f32_16x16x32_f16(a0l, bh, acc_l[0][nt], 0, 0, 0);
              acc_l[1][nt] = __builtin_amdgcn_mfma_f32_16x16x32_f16(a1h, bl, acc_l[1][nt], 0, 0, 0);
              acc_l[1][nt] = __builtin_amdgcn_mfma_f32_16x16x32_f16(a1l, bh, acc_l[1][nt], 0, 0, 0);
            }
          }
        }
      }
      // D frag -> LDS: row = mt*16 + 4*(lane>>4)+q, col = nt*16 + (lane&15)
      #pragma unroll
      for (int mt = 0; mt < 2; ++mt)
        #pragma unroll
        for (int nt = 0; nt < 4; ++nt)
          #pragma unroll
          for (int q = 0; q < 4; ++q) {
            int r = mt * 16 + (lane >> 4) * 4 + q;
            int n = nt * 16 + (lane & 15);
            part[wv][r][n] = acc_h[mt][nt][q] + INV2048 * acc_l[mt][nt][q];
          }
    }
    __syncthreads();
    if (active) {
      half_t* hbh = (layer == 0 ? h1hi : h2hi) + (p & 1) * 65536;
      half_t* hbl = (layer == 0 ? h1lo : h2lo) + (p & 1) * 65536;
      #pragma unroll
      for (int pp = 0; pp < 2; ++pp) {
        int pair = tid + pp * 256;
        int u = pair & 7, n = pair >> 3;
        float s0 = part[0][u][n]      + part[1][u][n]      + part[2][u][n]      + part[3][u][n]      + bsum[0];
        float s1 = part[0][8 + u][n]  + part[1][8 + u][n]  + part[2][8 + u][n]  + part[3][8 + u][n]  + bsum[1];
        float s2 = part[0][16 + u][n] + part[1][16 + u][n] + part[2][16 + u][n] + part[3][16 + u][n] + bsum[2];
        float s3 = part[0][24 + u][n] + part[1][24 + u][n] + part[2][24 + u][n] + part[3][24 + u][n] + bsum[3];
        float is = sigm(s0), fs = sigm(s1), gt = tanh_f(s2), os = sigm(s3);
        float& c = pp ? c1 : c0;
        c = fs * c + is * gt;
        float h = os * tanh_f(c);
        half_t hhi = (half_t)h;
        hbh[n * 1024 + wg * 8 + u] = hhi;
        hbl[n * 1024 + wg * 8 + u] = (half_t)((h - (float)hhi) * 2048.f);
        if (layer == 1) out[((long)t * 64 + n) * 1024 + wg * 8 + u] = h;  // f32 output
      }
    }
    __builtin_amdgcn_fence(__ATOMIC_RELEASE, "agent");
    grid.sync();
    __builtin_amdgcn_fence(__ATOMIC_ACQUIRE, "agent");
  }
}

extern "C" void kernel_launch(void* const* d_in, const int* in_sizes, int n_in,
                              void* d_out, int out_size, void* d_ws, size_t ws_size,
                              hipStream_t stream) {
  const int*   tokens = (const int*)d_in[0];
  const float* emb    = (const float*)d_in[1];
  const float* Wih    = (const float*)d_in[2];
  const float* Whh    = (const float*)d_in[3];
  const float* bih    = (const float*)d_in[4];
  const float* bhh    = (const float*)d_in[5];
  float* out = (float*)d_out;  // reference output dtype is float32

  half_t* wblob = (half_t*)d_ws;
  char* hb = (char*)d_ws + 67108864;
  half_t* h1hi = (half_t*)(hb);
  half_t* h1lo = (half_t*)(hb + 262144);
  half_t* h2hi = (half_t*)(hb + 524288);
  half_t* h2lo = (half_t*)(hb + 786432);

  hipLaunchKernelGGL(conv_w, dim3(65536), dim3(256), 0, stream, Wih, Whh, wblob);

  void* args[] = {(void*)&tokens, (void*)&emb, (void*)&bih, (void*)&bhh,
                  (void*)&wblob, (void*)&h1hi, (void*)&h1lo, (void*)&h2hi, (void*)&h2lo,
                  (void*)&out};
  hipLaunchCooperativeKernel((const void*)lstm_main, dim3(256), dim3(256), args, 0, stream);
}